// Round 12
// baseline (1323.605 us; speedup 1.0000x reference)
//
#include <hip/hip_runtime.h>
#include <hip/hip_bf16.h>
#include <hip/hip_fp16.h>

// ---------------- problem constants ----------------
constexpr int Bc = 32, Sc = 512, Tc = 128, Dc = 512, Ac = 512, Hc = 8;
constexpr int HDc = 64, FFc = 2048, Lc = 6, Vc = 500;
constexpr int NTOK = Bc * Tc;   // 4096
constexpr int NMEM = Bc * Sc;   // 16384

typedef unsigned short u16;
typedef __attribute__((ext_vector_type(8))) short short8;  // 8 bf16 (4 VGPRs)
typedef __attribute__((ext_vector_type(4))) float f32x4;   // MFMA accumulator

__device__ __forceinline__ u16 bfc(float x) {
  __hip_bfloat16 h = __float2bfloat16(x);
  return *reinterpret_cast<u16*>(&h);
}

// async global->LDS, 16B per lane. LDS dest = wave-uniform base + lane*16.
__device__ __forceinline__ void gload16(const void* g, void* l) {
  __builtin_amdgcn_global_load_lds(
      (const __attribute__((address_space(1))) unsigned int*)g,
      (__attribute__((address_space(3))) unsigned int*)l, 16, 0, 0);
}

// counted vmcnt wait + scheduler fence (rule #18: sched_barrier after inline waitcnt)
template <int N>
__device__ __forceinline__ void waitv() {
  if constexpr (N == 8)      asm volatile("s_waitcnt vmcnt(8)" ::: "memory");
  else if constexpr (N == 6) asm volatile("s_waitcnt vmcnt(6)" ::: "memory");
  else if constexpr (N == 4) asm volatile("s_waitcnt vmcnt(4)" ::: "memory");
  else if constexpr (N == 3) asm volatile("s_waitcnt vmcnt(3)" ::: "memory");
  else                       asm volatile("s_waitcnt vmcnt(0)" ::: "memory");
  __builtin_amdgcn_sched_barrier(0);
}
__device__ __forceinline__ void barrier_fenced() {
  __builtin_amdgcn_s_barrier();
  __builtin_amdgcn_sched_barrier(0);
}
__device__ __forceinline__ void lgk0_barrier() {
  asm volatile("s_waitcnt lgkmcnt(0)" ::: "memory");
  __builtin_amdgcn_sched_barrier(0);
  __builtin_amdgcn_s_barrier();
  __builtin_amdgcn_sched_barrier(0);
}

// ---------------- embedding + sinusoidal PE (fp32 X, bf16 Xb, row stats) ----------------
__global__ __launch_bounds__(256) void embed_pe_k(const int* __restrict__ ys,
                                                  const float* __restrict__ emb,
                                                  float* __restrict__ x,
                                                  u16* __restrict__ xb,
                                                  float* __restrict__ st0) {
  int tok = blockIdx.x;
  int t = tok & (Tc - 1);
  int id = ys[tok];
  int j = threadIdx.x;
  int d0 = 2 * j;
  const float cdiv = -9.210340371976184f / (float)Dc;
  float div = expf((float)d0 * cdiv);
  float ang = (float)t * div;
  float pe0 = sinf(ang), pe1 = cosf(ang);
  const float sc = 22.627416997969522f;  // sqrt(512)
  long base = (long)tok * Dc + d0;
  long ebase = (long)id * Dc + d0;
  float x0 = emb[ebase] * sc + pe0;
  float x1 = emb[ebase + 1] * sc + pe1;
  x[base] = x0; x[base + 1] = x1;
  xb[base] = bfc(x0); xb[base + 1] = bfc(x1);
  // row stats (single block per row -> plain store)
  float s = x0 + x1, s2 = x0 * x0 + x1 * x1;
  __shared__ float red[4], red2[4];
#pragma unroll
  for (int o = 32; o > 0; o >>= 1) {
    s  += __shfl_down(s, o);
    s2 += __shfl_down(s2, o);
  }
  if ((j & 63) == 0) { red[j >> 6] = s; red2[j >> 6] = s2; }
  __syncthreads();
  if (j == 0) {
    st0[(long)tok * 2]     = red[0] + red[1] + red[2] + red[3];
    st0[(long)tok * 2 + 1] = red2[0] + red2[1] + red2[2] + red2[3];
  }
}

// ---------------- weight transpose+convert (+optional LN-g fold on source rows) ----------
// W(K x N) fp32 -> Wt(Npad x K) bf16, Wt[n][k] = g[k]*W[k][n]
__global__ __launch_bounds__(256) void wtrans_k(const float* __restrict__ src,
                                                u16* __restrict__ dst,
                                                int K, int N, long srcStride, long dstStride,
                                                const float* __restrict__ gfold) {
  int z = blockIdx.z;
  src += z * srcStride;
  dst += z * dstStride;
  __shared__ float t[32][33];
  int n0 = blockIdx.x * 32, k0 = blockIdx.y * 32;
  int tx = threadIdx.x & 31, ty = threadIdx.x >> 5;  // 32 x 8
#pragma unroll
  for (int i = 0; i < 4; i++) {
    int n = n0 + tx;
    int k = k0 + ty + 8 * i;
    float v = (n < N) ? src[(long)k * N + n] : 0.0f;
    if (gfold) v *= gfold[(long)z * 512 + k];
    t[ty + 8 * i][tx] = v;
  }
  __syncthreads();
#pragma unroll
  for (int i = 0; i < 4; i++) {
    dst[(long)(n0 + ty + 8 * i) * K + k0 + tx] = bfc(t[tx][ty + 8 * i]);
  }
}

// ---------------- batched 512x512 weight transpose: 8 sets x 6 layers (+g fold) ----------
struct PtrPack8 { const float* p[8]; const float* g[8]; };
__global__ __launch_bounds__(256) void wtrans8_k(PtrPack8 P, u16* __restrict__ Wt,
                                                 long PLW) {
  int z = blockIdx.z;            // widx*6 + l
  int widx = z / 6, l = z - widx * 6;
  const float* src = P.p[widx] + (long)l * 262144;
  const float* gf = P.g[widx];
  u16* dst = Wt + (long)widx * 262144 + (long)l * PLW;
  __shared__ float t[32][33];
  int n0 = blockIdx.x * 32, k0 = blockIdx.y * 32;
  int tx = threadIdx.x & 31, ty = threadIdx.x >> 5;
#pragma unroll
  for (int i = 0; i < 4; i++) {
    int k = k0 + ty + 8 * i;
    float v = src[(long)k * 512 + n0 + tx];
    if (gf) v *= gf[(long)l * 512 + k];
    t[ty + 8 * i][tx] = v;
  }
  __syncthreads();
#pragma unroll
  for (int i = 0; i < 4; i++)
    dst[(long)(n0 + ty + 8 * i) * 512 + k0 + tx] = bfc(t[tx][ty + 8 * i]);
}

// ---------------- LN-fold colsum: c_j = sum_k g_k W_kj ; d_j = sum_k b_k W_kj + bias_j ----
struct ColPack {
  const float* W[5]; const float* g[5]; const float* b[5]; const float* bias[5];
};
__global__ __launch_bounds__(256) void colsum_k(ColPack P, float* __restrict__ cb,
                                                float* __restrict__ db) {
  int z = blockIdx.z;            // set*6 + l
  int set = z / 6, l = z - set * 6;
  const int Ns[5]   = {512, 512, 512, 512, 2048};
  const long Ws[5]  = {262144, 262144, 262144, 262144, 1048576};
  const int offs[5] = {0, 512, 1024, 1536, 2048};
  int N = Ns[set];
  int j = blockIdx.x * 256 + threadIdx.x;
  if (j >= N) return;
  const float* W = P.W[set] + (long)l * Ws[set];
  const float* g = P.g[set] + (long)l * 512;
  const float* b = P.b[set] + (long)l * 512;
  float ca = 0.f, da = 0.f;
  for (int k = 0; k < 512; k++) {
    float w = W[(long)k * N + j];
    ca += g[k] * w;
    da += b[k] * w;
  }
  cb[(long)l * 4096 + offs[set] + j] = ca;
  db[(long)l * 4096 + offs[set] + j] = da + P.bias[set][(long)l * N + j];
}

// ---------------- fp32 -> bf16 convert (memory input) ----------------
__global__ __launch_bounds__(256) void f2b_k(const float* __restrict__ in,
                                             u16* __restrict__ out, long n) {
  long i = ((long)blockIdx.x * 256 + threadIdx.x) * 4;
  if (i >= n) return;
  float4 v = *(const float4*)(in + i);
  ushort4 o;
  o.x = bfc(v.x); o.y = bfc(v.y); o.z = bfc(v.z); o.w = bfc(v.w);
  *(ushort4*)(out + i) = o;
}

// ---------------- bf16 MFMA GEMM: 3-buffer ring, prefetch-2, counted vmcnt, T1 swizzle ----
// 4 waves / 256 threads, BM = BMW*32, BN = 128 (R6/R8-proven schedule, 48KB LDS).
// LNFM: 0 none; 1 fold on all bi (stats_in + cp0..2/bias0..2 as c/d per bi);
//       2 fold only for bi==0 (merged CA: Q folded, K/V plain bias).
//   fold: v = rstd*(acc - mu*c[col]) + d[col]  ==  LN(x)@W + bias  (exact identity).
// SOUT: producer epilogue also writes Xb(bf16 copy of X) + per-row (sum,sumsq) stats
//       via LDS-reduced global atomicAdd (consumer kernel converts to mu/rstd).
template <int BMW, int OMODE, bool BIAS, bool RES, bool SWISH, bool NCH, bool MLEN,
          bool MERGE, int LNFM, bool SOUT>
__global__ __launch_bounds__(256) void mgemm_k(
    const u16* __restrict__ A, const u16* __restrict__ Bt,
    const float* __restrict__ bias0, const float* __restrict__ bias1,
    const float* __restrict__ bias2,
    void* __restrict__ Cv, const float* __restrict__ R, const int* __restrict__ mlens,
    const u16* __restrict__ A2, void* __restrict__ Cv2, int Mq,
    const float* __restrict__ cp0, const float* __restrict__ cp1,
    const float* __restrict__ cp2,
    const float* __restrict__ stats_in, float* __restrict__ stats_out,
    u16* __restrict__ xb_out,
    int N, int K, int lda, int ldb, int ldc, int nbi,
    long batAo, long batAi, long batBo, long batBi, long batCo, long batCi) {
  constexpr int BM = BMW * 32;
  constexpr int LPS = (BM == 128 ? 2 : 1) + 2;   // global_load_lds per STAGE per wave

  // T1: bijective XCD-aware swizzle (m204) over the flattened grid.
  int gx = gridDim.x, gy = gridDim.y;
  int nwg = gx * gy * gridDim.z;
  int orig = blockIdx.x + gx * (blockIdx.y + gy * blockIdx.z);
  int q = nwg >> 3, r = nwg & 7, xcd = orig & 7, off = orig >> 3;
  int wgid = (xcd < r ? xcd * (q + 1) : r * (q + 1) + (xcd - r) * q) + off;
  int bxi = wgid % gx; int tmp = wgid / gx;
  int byi = tmp % gy;  int bzi = tmp / gy;

  int z = bzi;
  int bo = z / nbi, bi = z - bo * nbi;
  int m0 = byi * BM, n0 = bxi * 128;

  const u16* Ab;
  long coff;
  void* Cbase;
  if constexpr (MERGE) {
    if (bi == 0) {
      if (m0 >= Mq) return;            // Q part has fewer rows
      Ab = A;
      coff = 0; Cbase = Cv;
    } else {
      if (MLEN && (m0 & 511) >= mlens[m0 >> 9]) return;
      Ab = A2;
      coff = (long)(bi - 1) * batCi; Cbase = Cv2;
    }
  } else {
    if constexpr (MLEN) {
      if ((m0 & 511) >= mlens[m0 >> 9]) return;
    }
    Ab = A + bo * batAo + bi * batAi;
    coff = bo * batCo + bi * batCi;
    Cbase = Cv;
  }
  const u16* Bb = Bt + bo * batBo + bi * batBi;
  const float* bias = nullptr;
  if constexpr (BIAS) bias = (bi == 0) ? bias0 : ((bi == 1) ? bias1 : bias2);

  __shared__ __align__(16) u16 As[3][BM * 32];
  __shared__ __align__(16) u16 Bs[3][128 * 32];
  __shared__ float statLDS[BM][2];

  int tid = threadIdx.x;
  int lane = tid & 63, wid = tid >> 6;
  int wm = wid >> 1, wn = wid & 1;
  int fr = lane & 15, grp = lane >> 4;

  f32x4 acc[BMW][4];
#pragma unroll
  for (int i = 0; i < BMW; i++)
#pragma unroll
    for (int j = 0; j < 4; j++) acc[i][j] = (f32x4){0.f, 0.f, 0.f, 0.f};

  const u16* ga = Ab + (long)(m0 + (tid >> 2)) * lda + ((tid & 3) << 3);
  const u16* gb = Bb + (long)(n0 + (tid >> 2)) * ldb + ((tid & 3) << 3);

  auto STAGE = [&](int buf, int kt) {
    u16* lA = &As[buf][tid * 8];
    u16* lB = &Bs[buf][tid * 8];
    gload16(ga + kt, lA);
    if constexpr (BM == 128) gload16(ga + kt + (long)64 * lda, lA + 2048);
    gload16(gb + kt, lB);
    gload16(gb + kt + (long)64 * ldb, lB + 2048);
  };

  auto COMPUTE = [&](int buf) {
    short8 av[BMW], bv[4];
#pragma unroll
    for (int i = 0; i < BMW; i++)
      av[i] = *(const short8*)&As[buf][(wm * BMW * 16 + i * 16 + fr) * 32 + grp * 8];
#pragma unroll
    for (int j = 0; j < 4; j++)
      bv[j] = *(const short8*)&Bs[buf][(wn * 64 + j * 16 + fr) * 32 + grp * 8];
#pragma unroll
    for (int i = 0; i < BMW; i++)
#pragma unroll
      for (int j = 0; j < 4; j++)
        acc[i][j] = __builtin_amdgcn_mfma_f32_16x16x32_bf16(av[i], bv[j], acc[i][j], 0, 0, 0);
  };

  int NT = K >> 5;                 // K/32 k-steps; all call sites have NT >= 16
  STAGE(0, 0);
  STAGE(1, 32);
  int cbuf = 0, sbuf = 2, kt = 64;
  for (int t = 0; t < NT - 2; ++t) {
    STAGE(sbuf, kt); kt += 32;     // tile t+2 into ring
    waitv<2 * LPS>();              // tile t's loads complete; t+1,t+2 stay in flight
    barrier_fenced();              // buf ready for all waves
    COMPUTE(cbuf);
    lgk0_barrier();                // all waves done reading buf (WAR for next STAGE)
    sbuf = cbuf; cbuf = (cbuf == 2) ? 0 : cbuf + 1;
  }
  waitv<LPS>();  barrier_fenced(); COMPUTE(cbuf); lgk0_barrier();
  cbuf = (cbuf == 2) ? 0 : cbuf + 1;
  waitv<0>();    barrier_fenced(); COMPUTE(cbuf);

  bool dofold = (LNFM == 1) || (LNFM == 2 && bi == 0);
  float psum[BMW * 4], psq[BMW * 4];
  if constexpr (SOUT) {
#pragma unroll
    for (int t2 = 0; t2 < BMW * 4; t2++) { psum[t2] = 0.f; psq[t2] = 0.f; }
  }

  int rbase = m0 + wm * BMW * 16 + grp * 4;
  int cbase = n0 + wn * 64 + fr;
#pragma unroll
  for (int i = 0; i < BMW; i++) {
    float mu_r[4], rs_r[4];
    if constexpr (LNFM != 0) {
      if (dofold) {
#pragma unroll
        for (int r2 = 0; r2 < 4; r2++) {
          int row = rbase + i * 16 + r2;
          float s = stats_in[(long)row * 2], s2 = stats_in[(long)row * 2 + 1];
          float m = s * (1.0f / 512.0f);
          float var = s2 * (1.0f / 512.0f) - m * m;
          mu_r[r2] = m; rs_r[r2] = rsqrtf(var + 1e-5f);
        }
      }
    }
#pragma unroll
    for (int j = 0; j < 4; j++) {
      int col = cbase + j * 16;
      if (NCH && col >= N) continue;
      float bb = 0.0f, cc = 0.0f;
      if constexpr (BIAS) bb = bias[col];
      if constexpr (LNFM != 0) {
        if (dofold) {
          const float* cp = (bi == 0) ? cp0 : ((bi == 1) ? cp1 : cp2);
          cc = cp[col];
        }
      }
#pragma unroll
      for (int r2 = 0; r2 < 4; r2++) {
        int row = rbase + i * 16 + r2;
        float v = acc[i][j][r2];
        if (LNFM != 0 && dofold) v = rs_r[r2] * (v - mu_r[r2] * cc) + bb;
        else if constexpr (BIAS) v += bb;
        long idx = coff + (long)row * ldc + col;
        if constexpr (RES) v += R[idx];
        if constexpr (SWISH) v = v / (1.0f + expf(-v));
        if constexpr (OMODE == 0) ((u16*)Cbase)[idx] = bfc(v);
        else ((float*)Cbase)[idx] = v;
        if constexpr (SOUT) {
          xb_out[idx] = bfc(v);
          psum[i * 4 + r2] += v;
          psq[i * 4 + r2] += v * v;
        }
      }
    }
  }

  if constexpr (SOUT) {
    __syncthreads();
    if (tid < BM) { statLDS[tid][0] = 0.f; statLDS[tid][1] = 0.f; }
    __syncthreads();
#pragma unroll
    for (int i = 0; i < BMW; i++)
#pragma unroll
      for (int r2 = 0; r2 < 4; r2++) {
        int rl = wm * BMW * 16 + grp * 4 + i * 16 + r2;
        atomicAdd(&statLDS[rl][0], psum[i * 4 + r2]);
        atomicAdd(&statLDS[rl][1], psq[i * 4 + r2]);
      }
    __syncthreads();
    if (tid < BM) {
      atomicAdd(&stats_out[(long)(m0 + tid) * 2],     statLDS[tid][0]);
      atomicAdd(&stats_out[(long)(m0 + tid) * 2 + 1], statLDS[tid][1]);
    }
  }
}

// ---------------- fused flash attention (unchanged from R8/R11) ----------------
template <int SKV, int KVBLK, bool CAUSAL, int IQ>
__global__ __launch_bounds__(256) void fattn_k(
    const u16* __restrict__ Q, const u16* __restrict__ Kg, const u16* __restrict__ Vg,
    u16* __restrict__ O, const int* __restrict__ lens) {
  constexpr int NJ  = KVBLK / 16;
  constexpr int NKV = KVBLK / 32;
  constexpr int NT  = SKV / KVBLK;
  constexpr int KST = 72;
  constexpr int VST = KVBLK + 8;
  constexpr int WR  = 16 * IQ;
  constexpr int WGR = 64 * IQ;
  constexpr int CH  = KVBLK / 32;

  __shared__ __align__(16) u16 Ks[KVBLK * KST];
  __shared__ __align__(16) u16 Vs[64 * VST];
  __shared__ __align__(16) u16 Ps[WGR * VST];

  int bh = blockIdx.x; int b = bh >> 3, h = bh & 7;
  int row00 = blockIdx.y * WGR;
  int tid = threadIdx.x, lane = tid & 63, wid = tid >> 6;
  int fr = lane & 15, grp = lane >> 4;
  int len = lens[b];
  int row0w = row00 + wid * WR;

  short8 qa[IQ][2];
  {
    const u16* qp = Q + ((long)b * Tc + row0w + fr) * 512 + h * 64 + grp * 8;
#pragma unroll
    for (int i = 0; i < IQ; i++)
#pragma unroll
      for (int k2 = 0; k2 < 2; k2++)
        qa[i][k2] = *(const short8*)(qp + (long)i * 16 * 512 + k2 * 32);
  }

  float m_run[IQ][4], l_run[IQ][4];
  f32x4 acc_o[IQ][4];
#pragma unroll
  for (int i = 0; i < IQ; i++)
#pragma unroll
    for (int r = 0; r < 4; r++) { m_run[i][r] = -1e30f; l_run[i][r] = 0.0f; }
#pragma unroll
  for (int i = 0; i < IQ; i++)
#pragma unroll
    for (int j = 0; j < 4; j++) acc_o[i][j] = (f32x4){0.f, 0.f, 0.f, 0.f};

  const u16* Kbase = Kg + ((long)b * SKV) * 512 + h * 64;
  const u16* Vbase = Vg + ((long)b * SKV) * 512 + h * 64;

  int NTeff = NT;
  if constexpr (CAUSAL) NTeff = (row00 + WGR - 1) / KVBLK + 1;
  if (NTeff > NT) NTeff = NT;
  int lenT = (len + KVBLK - 1) / KVBLK;
  if (lenT < NTeff) NTeff = lenT;

  short8 kreg[CH], vreg[CH];
#pragma unroll
  for (int c = 0; c < CH; c++) {
    int idx = tid + 256 * c; int kv = idx >> 3, s = idx & 7;
    kreg[c] = *(const short8*)(Kbase + (long)kv * 512 + s * 8);
    vreg[c] = *(const short8*)(Vbase + (long)kv * 512 + s * 8);
  }

  for (int t = 0; t < NTeff; t++) {
    int kv0 = t * KVBLK;
    __syncthreads();
#pragma unroll
    for (int c = 0; c < CH; c++) {
      int idx = tid + 256 * c; int kv = idx >> 3, s = idx & 7;
      *(short8*)&Ks[kv * KST + s * 8] = kreg[c];
#pragma unroll
      for (int j = 0; j < 8; j++)
        Vs[(s * 8 + j) * VST + kv] = (u16)vreg[c][j];
    }
    __syncthreads();
    if (t + 1 < NTeff) {
      int kvn = kv0 + KVBLK;
#pragma unroll
      for (int c = 0; c < CH; c++) {
        int idx = tid + 256 * c; int kv = idx >> 3, s = idx & 7;
        kreg[c] = *(const short8*)(Kbase + (long)(kvn + kv) * 512 + s * 8);
        vreg[c] = *(const short8*)(Vbase + (long)(kvn + kv) * 512 + s * 8);
      }
    }

    int jmax = NJ, kvmax = NKV, jmaxW = NJ;
    if constexpr (CAUSAL) {
      jmax = (row0w + WR - 1 - kv0) / 16 + 1;
      if (jmax > NJ) jmax = NJ;
      kvmax = (row0w + WR - 1 - kv0) / 32 + 1;
      if (kvmax > NKV) kvmax = NKV;
      jmaxW = 2 * kvmax;
      if (jmaxW > NJ) jmaxW = NJ;
    }

    f32x4 accs[IQ][NJ];
    __builtin_amdgcn_s_setprio(1);
#pragma unroll
    for (int j = 0; j < NJ; j++) {
      if (CAUSAL && j >= jmax) continue;
      short8 bv0 = *(const short8*)&Ks[(j * 16 + fr) * KST + grp * 8];
      short8 bv1 = *(const short8*)&Ks[(j * 16 + fr) * KST + 32 + grp * 8];
#pragma unroll
      for (int i = 0; i < IQ; i++) {
        f32x4 a = __builtin_amdgcn_mfma_f32_16x16x32_bf16(qa[i][0], bv0, (f32x4){0.f,0.f,0.f,0.f}, 0, 0, 0);
        accs[i][j] = __builtin_amdgcn_mfma_f32_16x16x32_bf16(qa[i][1], bv1, a, 0, 0, 0);
      }
    }
    __builtin_amdgcn_s_setprio(0);

    float alpha[IQ][4];
#pragma unroll
    for (int i = 0; i < IQ; i++) {
#pragma unroll
      for (int r = 0; r < 4; r++) {
        int qrow = row0w + i * 16 + grp * 4 + r;
        float vmax = -1e30f;
#pragma unroll
        for (int j = 0; j < NJ; j++) {
          if (CAUSAL && j >= jmax) continue;
          int kvb = kv0 + j * 16 + fr;
          float s = accs[i][j][r] * 0.125f;
          bool msk = (kvb >= len) || (CAUSAL && kvb > qrow);
          s = msk ? -1e30f : s;
          accs[i][j][r] = s;
          vmax = fmaxf(vmax, s);
        }
        vmax = fmaxf(vmax, __shfl_xor(vmax, 1));
        vmax = fmaxf(vmax, __shfl_xor(vmax, 2));
        vmax = fmaxf(vmax, __shfl_xor(vmax, 4));
        vmax = fmaxf(vmax, __shfl_xor(vmax, 8));
        float mn = fmaxf(m_run[i][r], vmax);
        float al = __expf(m_run[i][r] - mn);
        m_run[i][r] = mn;
        alpha[i][r] = al;
        float rs = 0.0f;
#pragma unroll
        for (int j = 0; j < NJ; j++) {
          if (CAUSAL && j >= jmax) continue;
          float p = __expf(accs[i][j][r] - mn);
          accs[i][j][r] = p;
          rs += p;
        }
        rs += __shfl_xor(rs, 1);
        rs += __shfl_xor(rs, 2);
        rs += __shfl_xor(rs, 4);
        rs += __shfl_xor(rs, 8);
        l_run[i][r] = l_run[i][r] * al + rs;
      }
    }

#pragma unroll
    for (int i = 0; i < IQ; i++)
#pragma unroll
      for (int j = 0; j < NJ; j++) {
        if (CAUSAL && j >= jmaxW) continue;
#pragma unroll
        for (int r = 0; r < 4; r++) {
          int prow = wid * WR + i * 16 + grp * 4 + r;
          float pv = (CAUSAL && j >= jmax) ? 0.0f : accs[i][j][r];
          Ps[prow * VST + j * 16 + fr] = bfc(pv);
        }
      }

#pragma unroll
    for (int i = 0; i < IQ; i++)
#pragma unroll
      for (int jd = 0; jd < 4; jd++)
#pragma unroll
        for (int r = 0; r < 4; r++)
          acc_o[i][jd][r] *= alpha[i][r];

    __builtin_amdgcn_s_setprio(1);
#pragma unroll
    for (int kk = 0; kk < NKV; kk++) {
      if (CAUSAL && kk >= kvmax) continue;
      short8 pa[IQ];
#pragma unroll
      for (int i = 0; i < IQ; i++)
        pa[i] = *(const short8*)&Ps[(wid * WR + i * 16 + fr) * VST + kk * 32 + grp * 8];
#pragma unroll
      for (int jd = 0; jd < 4; jd++) {
        short8 vb = *(const short8*)&Vs[(jd * 16 + fr) * VST + kk * 32 + grp * 8];
#pragma unroll
        for (int i = 0; i < IQ; i++)
          acc_o[i][jd] = __builtin_amdgcn_mfma_f32_16x16x32_bf16(pa[i], vb, acc_o[i][jd], 0, 0, 0);
      }
    }
    __builtin_amdgcn_s_setprio(0);
  }

#pragma unroll
  for (int i = 0; i < IQ; i++) {
#pragma unroll
    for (int r = 0; r < 4; r++) {
      float inv = 1.0f / l_run[i][r];
      long tok = (long)b * Tc + row0w + i * 16 + grp * 4 + r;
#pragma unroll
      for (int jd = 0; jd < 4; jd++)
        O[tok * 512 + h * 64 + jd * 16 + fr] = bfc(acc_o[i][jd][r] * inv);
    }
  }
}

// ---------------- host launcher ----------------
extern "C" void kernel_launch(void* const* d_in, const int* in_sizes, int n_in,
                              void* d_out, int out_size, void* d_ws, size_t ws_size,
                              hipStream_t stream) {
  const float* memory   = (const float*)d_in[0];
  const int*   mem_lens = (const int*)d_in[1];
  const int*   ys       = (const int*)d_in[2];
  const int*   ys_lens  = (const int*)d_in[3];
  const float* emb      = (const float*)d_in[4];
  const float* w_out    = (const float*)d_in[5];
  const float* b_out    = (const float*)d_in[6];
  const float* pp[26];
  for (int i = 0; i < 26; i++) pp[i] = (const float*)d_in[7 + i];

  // ---- ws layout (~131.5 MB of the 256 MiB ws) ----
  constexpr long PLW = 4194304;  // bf16 elems of transposed weights per layer
  constexpr long OFF_SAQ = 0, OFF_SAK = 262144, OFF_SAV = 524288, OFF_SAO = 786432,
                 OFF_CAQ = 1048576, OFF_CAK = 1310720, OFF_CAV = 1572864,
                 OFF_CAO = 1835008, OFF_FF1 = 2097152, OFF_FF2 = 3145728,
                 OFF_WOUT = 6 * PLW;
  u16*   Wt    = (u16*)d_ws;                          // 25,427,968 u16
  float* X     = (float*)(Wt + 25427968);             // 2,097,152 f32
  u16*   TO    = (u16*)(X + 2097152);                 // 2,097,152 bf16 (attn out)
  u16*   QKV   = TO + 2097152;                        // 3 x 2,097,152 bf16
  u16*   memb  = QKV + 3 * 2097152;                   // 8,388,608 bf16
  u16*   Kb    = memb + 8388608;                      // 8,388,608 bf16 (cross K)
  u16*   SCR   = Kb + 8388608;                        // 8,388,608 bf16 (CA V / FF hidden)
  u16*   Xb    = SCR + 8388608;                       // 2,097,152 bf16 (residual, bf16)
  float* stats = (float*)(Xb + 2097152);              // 19 x 4096 x 2 f32
  float* c_buf = stats + 19 * 8192;                   // 6 x 4096 f32
  float* d_buf = c_buf + 6 * 4096;                    // 6 x 4096 f32
  float* OUT   = (float*)d_out;

  // zero the LN stats accumulators (producers atomicAdd into them each launch)
  hipMemsetAsync(stats, 0, 19 * 8192 * sizeof(float), stream);

  // weight transposes, with LN-g folded into consumer weights
  PtrPack8 P8;
  P8.p[0] = pp[2];  P8.p[1] = pp[4];  P8.p[2] = pp[6];  P8.p[3] = pp[8];
  P8.p[4] = pp[12]; P8.p[5] = pp[14]; P8.p[6] = pp[16]; P8.p[7] = pp[18];
  P8.g[0] = pp[0];  P8.g[1] = pp[0];  P8.g[2] = pp[0];  P8.g[3] = nullptr;
  P8.g[4] = pp[10]; P8.g[5] = nullptr; P8.g[6] = nullptr; P8.g[7] = nullptr;
  wtrans8_k<<<dim3(16, 16, 48), 256, 0, stream>>>(P8, Wt, PLW);
  wtrans_k<<<dim3(64, 16, Lc), 256, 0, stream>>>(pp[22], Wt + OFF_FF1, 512, 2048, 1048576, PLW, pp[20]);
  wtrans_k<<<dim3(16, 64, Lc), 256, 0, stream>>>(pp[24], Wt + OFF_FF2, 2048, 512, 1048576, PLW, nullptr);
  wtrans_k<<<dim3(16, 16, 1), 256, 0, stream>>>(w_out, Wt + OFF_WOUT, 512, 500, 0, 0, nullptr);

  // LN-fold colsums: sets {saq, sak, sav, caq, ff1}
  ColPack CP;
  CP.W[0] = pp[2];  CP.W[1] = pp[4];  CP.W[2] = pp[6];  CP.W[3] = pp[12]; CP.W[4] = pp[22];
  CP.g[0] = pp[0];  CP.g[1] = pp[0];  CP.g[2] = pp[0];  CP.g[3] = pp[10]; CP.g[4] = pp[20];
  CP.b[0] = pp[1];  CP.b[1] = pp[1];  CP.b[2] = pp[1];  CP.b[3] = pp[11]; CP.b[4] = pp[21];
  CP.bias[0] = pp[3]; CP.bias[1] = pp[5]; CP.bias[2] = pp[7]; CP.bias[3] = pp[13]; CP.bias[4] = pp[23];
  colsum_k<<<dim3(8, 1, 30), 256, 0, stream>>>(CP, c_buf, d_buf);

  f2b_k<<<(NMEM * Dc / 4 + 255) / 256, 256, 0, stream>>>(memory, memb, (long)NMEM * Dc);
  embed_pe_k<<<NTOK, 256, 0, stream>>>(ys, emb, X, Xb, stats);  // stats buf 0

  for (int l = 0; l < Lc; l++) {
    const u16* WtL = Wt + (long)l * PLW;
    const float* cL = c_buf + (long)l * 4096;
    const float* dL = d_buf + (long)l * 4096;
    float* stSA = stats + (long)(3 * l) * 8192;       // ln_sa stats (from FF2[l-1]/embed)
    float* stCA = stats + (long)(3 * l + 1) * 8192;   // ln_ca stats (from SA-O)
    float* stFF = stats + (long)(3 * l + 2) * 8192;   // ln_ff stats (from CA-O)
    float* stNX = stats + (long)(3 * l + 3) * 8192;   // next layer ln_sa (from FF2)

    // ======== self-attention ========
    // QKV with LN fold (A = raw residual bf16)
    mgemm_k<4, 0, true, false, false, false, false, false, 1, false><<<dim3(4, 32, 3), 256, 0, stream>>>(
        Xb, WtL + OFF_SAQ, dL + 0, dL + 512, dL + 1024,
        QKV, nullptr, nullptr, nullptr, nullptr, 0,
        cL + 0, cL + 512, cL + 1024, stSA, nullptr, nullptr,
        512, 512, 512, 512, 512, 3, 0, 0, 0, 262144, 0, 2097152);
    fattn_k<128, 128, true, 1><<<dim3(256, 2), 256, 0, stream>>>(
        QKV, QKV + 2097152, QKV + 2 * 2097152, TO, ys_lens);
    // O-proj + residual -> X, Xb, stats(ln_ca)
    mgemm_k<2, 1, true, true, false, false, false, false, 0, true><<<dim3(4, 64, 1), 256, 0, stream>>>(
        TO, WtL + OFF_SAO, pp[9] + (long)l * Dc, nullptr, nullptr, X, X, nullptr,
        nullptr, nullptr, 0,
        nullptr, nullptr, nullptr, nullptr, stCA, Xb,
        512, 512, 512, 512, 512, 1, 0, 0, 0, 0, 0, 0);

    // ======== cross-attention ========
    // merged: Q (bi=0, LN-folded, A=Xb) + K,V (bi=1,2, A2=memb -> Kb, SCR)
    mgemm_k<4, 0, true, false, false, false, true, true, 2, false><<<dim3(4, 128, 3), 256, 0, stream>>>(
        Xb, WtL + OFF_CAQ, dL + 1536, pp[15] + (long)l * Ac, pp[17] + (long)l * Ac,
        QKV, nullptr, mem_lens, memb, Kb, 4096,
        cL + 1536, nullptr, nullptr, stCA, nullptr, nullptr,
        512, 512, 512, 512, 512, 3, 0, 0, 0, 262144, 0, 8388608);
    fattn_k<512, 128, false, 1><<<dim3(256, 2), 256, 0, stream>>>(
        QKV, Kb, SCR, TO, mem_lens);
    mgemm_k<2, 1, true, true, false, false, false, false, 0, true><<<dim3(4, 64, 1), 256, 0, stream>>>(
        TO, WtL + OFF_CAO, pp[19] + (long)l * Dc, nullptr, nullptr, X, X, nullptr,
        nullptr, nullptr, 0,
        nullptr, nullptr, nullptr, nullptr, stFF, Xb,
        512, 512, 512, 512, 512, 1, 0, 0, 0, 0, 0, 0);

    // ======== feed-forward ========
    // FF1 with LN fold + Swish
    mgemm_k<4, 0, true, false, true, false, false, false, 1, false><<<dim3(16, 32, 1), 256, 0, stream>>>(
        Xb, WtL + OFF_FF1, dL + 2048, nullptr, nullptr, SCR, nullptr, nullptr,
        nullptr, nullptr, 0,
        cL + 2048, nullptr, nullptr, stFF, nullptr, nullptr,
        2048, 512, 512, 512, 2048, 1, 0, 0, 0, 0, 0, 0);
    mgemm_k<2, 1, true, true, false, false, false, false, 0, true><<<dim3(4, 64, 1), 256, 0, stream>>>(
        SCR, WtL + OFF_FF2, pp[25] + (long)l * Dc, nullptr, nullptr, X, X, nullptr,
        nullptr, nullptr, 0,
        nullptr, nullptr, nullptr, nullptr, stNX, Xb,
        512, 2048, 2048, 2048, 512, 1, 0, 0, 0, 0, 0, 0);
  }

  // final projection reads Xb directly (reference has no LN before w_out)
  mgemm_k<2, 1, true, false, false, true, false, false, 0, false><<<dim3(4, 64, 1), 256, 0, stream>>>(
      Xb, Wt + OFF_WOUT, b_out, nullptr, nullptr, OUT, nullptr, nullptr,
      nullptr, nullptr, 0,
      nullptr, nullptr, nullptr, nullptr, nullptr, nullptr,
      500, 512, 512, 512, 500, 1, 0, 0, 0, 0, 0, 0);
}

// Round 13
// 1198.976 us; speedup vs baseline: 1.1039x; 1.1039x over previous
//
#include <hip/hip_runtime.h>
#include <hip/hip_bf16.h>
#include <hip/hip_fp16.h>

// ---------------- problem constants ----------------
constexpr int Bc = 32, Sc = 512, Tc = 128, Dc = 512, Ac = 512, Hc = 8;
constexpr int HDc = 64, FFc = 2048, Lc = 6, Vc = 500;
constexpr int NTOK = Bc * Tc;   // 4096
constexpr int NMEM = Bc * Sc;   // 16384

typedef unsigned short u16;
typedef __attribute__((ext_vector_type(8))) short short8;  // 8 bf16 (4 VGPRs)
typedef __attribute__((ext_vector_type(4))) float f32x4;   // MFMA accumulator

__device__ __forceinline__ u16 bfc(float x) {
  __hip_bfloat16 h = __float2bfloat16(x);
  return *reinterpret_cast<u16*>(&h);
}

// async global->LDS, 16B per lane. LDS dest = wave-uniform base + lane*16.
__device__ __forceinline__ void gload16(const void* g, void* l) {
  __builtin_amdgcn_global_load_lds(
      (const __attribute__((address_space(1))) unsigned int*)g,
      (__attribute__((address_space(3))) unsigned int*)l, 16, 0, 0);
}

// counted vmcnt wait + scheduler fence (rule #18: sched_barrier after inline waitcnt)
template <int N>
__device__ __forceinline__ void waitv() {
  if constexpr (N == 8)      asm volatile("s_waitcnt vmcnt(8)" ::: "memory");
  else if constexpr (N == 6) asm volatile("s_waitcnt vmcnt(6)" ::: "memory");
  else if constexpr (N == 4) asm volatile("s_waitcnt vmcnt(4)" ::: "memory");
  else if constexpr (N == 3) asm volatile("s_waitcnt vmcnt(3)" ::: "memory");
  else                       asm volatile("s_waitcnt vmcnt(0)" ::: "memory");
  __builtin_amdgcn_sched_barrier(0);
}
__device__ __forceinline__ void barrier_fenced() {
  __builtin_amdgcn_s_barrier();
  __builtin_amdgcn_sched_barrier(0);
}
__device__ __forceinline__ void lgk0_barrier() {
  asm volatile("s_waitcnt lgkmcnt(0)" ::: "memory");
  __builtin_amdgcn_sched_barrier(0);
  __builtin_amdgcn_s_barrier();
  __builtin_amdgcn_sched_barrier(0);
}

__device__ __forceinline__ float wave_sum(float v) {
#pragma unroll
  for (int o = 32; o > 0; o >>= 1) v += __shfl_down(v, o);
  return v;
}

// ---------------- embedding + sinusoidal PE (fp32 residual stream) ----------------
__global__ __launch_bounds__(256) void embed_pe_k(const int* __restrict__ ys,
                                                  const float* __restrict__ emb,
                                                  float* __restrict__ x) {
  int tok = blockIdx.x;
  int t = tok & (Tc - 1);
  int id = ys[tok];
  int j = threadIdx.x;
  int d0 = 2 * j;
  const float cdiv = -9.210340371976184f / (float)Dc;
  float div = expf((float)d0 * cdiv);
  float ang = (float)t * div;
  float pe0 = sinf(ang), pe1 = cosf(ang);
  const float sc = 22.627416997969522f;  // sqrt(512)
  long base = (long)tok * Dc + d0;
  long ebase = (long)id * Dc + d0;
  x[base]     = emb[ebase]     * sc + pe0;
  x[base + 1] = emb[ebase + 1] * sc + pe1;
}

// ---------------- layernorm fp32 -> bf16 (one-pass: sum + sumsq together) ----------------
__global__ __launch_bounds__(256) void layernorm_k(const float* __restrict__ x,
                                                   const float* __restrict__ g,
                                                   const float* __restrict__ bta,
                                                   u16* __restrict__ out) {
  int row = blockIdx.x;
  int tid = threadIdx.x;
  const float* xr = x + (long)row * Dc;
  float2 xv = *(const float2*)(xr + tid * 2);
  float s  = xv.x + xv.y;
  float s2 = xv.x * xv.x + xv.y * xv.y;
  __shared__ float red[4], red2[4];
#pragma unroll
  for (int o = 32; o > 0; o >>= 1) {
    s  += __shfl_down(s, o);
    s2 += __shfl_down(s2, o);
  }
  if ((tid & 63) == 0) { red[tid >> 6] = s; red2[tid >> 6] = s2; }
  __syncthreads();
  float mean = (red[0] + red[1] + red[2] + red[3]) * (1.0f / Dc);
  float ms   = (red2[0] + red2[1] + red2[2] + red2[3]) * (1.0f / Dc);
  float var  = ms - mean * mean;
  float rstd = rsqrtf(var + 1e-5f);
  float dx0 = xv.x - mean, dx1 = xv.y - mean;
  ushort2 o;
  o.x = bfc(dx0 * rstd * g[2 * tid] + bta[2 * tid]);
  o.y = bfc(dx1 * rstd * g[2 * tid + 1] + bta[2 * tid + 1]);
  *(ushort2*)(out + (long)row * Dc + tid * 2) = o;
}

// ---------------- weight transpose+convert: W(K x N) fp32 -> Wt(Npad x K) bf16 ----------------
__global__ __launch_bounds__(256) void wtrans_k(const float* __restrict__ src,
                                                u16* __restrict__ dst,
                                                int K, int N, long srcStride, long dstStride) {
  int z = blockIdx.z;
  src += z * srcStride;
  dst += z * dstStride;
  __shared__ float t[32][33];
  int n0 = blockIdx.x * 32, k0 = blockIdx.y * 32;
  int tx = threadIdx.x & 31, ty = threadIdx.x >> 5;  // 32 x 8
#pragma unroll
  for (int i = 0; i < 4; i++) {
    int n = n0 + tx;
    t[ty + 8 * i][tx] = (n < N) ? src[(long)(k0 + ty + 8 * i) * N + n] : 0.0f;
  }
  __syncthreads();
#pragma unroll
  for (int i = 0; i < 4; i++) {
    dst[(long)(n0 + ty + 8 * i) * K + k0 + tx] = bfc(t[tx][ty + 8 * i]);
  }
}

// ---------------- batched 512x512 weight transpose: 8 weight sets x 6 layers ----------------
struct PtrPack8 { const float* p[8]; };
__global__ __launch_bounds__(256) void wtrans8_k(PtrPack8 P, u16* __restrict__ Wt,
                                                 long PLW) {
  int z = blockIdx.z;            // widx*6 + l
  int widx = z / 6, l = z - widx * 6;
  const float* src = P.p[widx] + (long)l * 262144;
  u16* dst = Wt + (long)widx * 262144 + (long)l * PLW;
  __shared__ float t[32][33];
  int n0 = blockIdx.x * 32, k0 = blockIdx.y * 32;
  int tx = threadIdx.x & 31, ty = threadIdx.x >> 5;
#pragma unroll
  for (int i = 0; i < 4; i++)
    t[ty + 8 * i][tx] = src[(long)(k0 + ty + 8 * i) * 512 + n0 + tx];
  __syncthreads();
#pragma unroll
  for (int i = 0; i < 4; i++)
    dst[(long)(n0 + ty + 8 * i) * 512 + k0 + tx] = bfc(t[tx][ty + 8 * i]);
}

// ---------------- fp32 -> bf16 convert ----------------
__global__ __launch_bounds__(256) void f2b_k(const float* __restrict__ in,
                                             u16* __restrict__ out, long n) {
  long i = ((long)blockIdx.x * 256 + threadIdx.x) * 4;
  if (i >= n) return;
  float4 v = *(const float4*)(in + i);
  ushort4 o;
  o.x = bfc(v.x); o.y = bfc(v.y); o.z = bfc(v.z); o.w = bfc(v.w);
  *(ushort4*)(out + i) = o;
}

// ---------------- bf16 MFMA GEMM: 3-buffer ring, prefetch-2, counted vmcnt, T1 swizzle ----
// 4 waves / 256 threads, BM = BMW*32, BN = 128. (R6/R8/R11-proven schedule & config:
// 48KB LDS -> 3 blocks/CU. Measured regressions from here: 4-buffer/64KB ring (R7),
// 8-wave BM=256/72KB (R10), LN-fold epilogues (R12).)
template <int BMW, int OMODE, bool BIAS, bool RES, bool SWISH, bool NCH, bool MLEN, bool MERGE>
__global__ __launch_bounds__(256) void mgemm_k(
    const u16* __restrict__ A, const u16* __restrict__ Bt,
    const float* __restrict__ bias0, const float* __restrict__ bias1,
    const float* __restrict__ bias2,
    void* __restrict__ Cv, const float* __restrict__ R, const int* __restrict__ mlens,
    const u16* __restrict__ A2, void* __restrict__ Cv2, int Mq,
    int N, int K, int lda, int ldb, int ldc, int nbi,
    long batAo, long batAi, long batBo, long batBi, long batCo, long batCi) {
  constexpr int BM = BMW * 32;
  constexpr int LPS = (BM == 128 ? 2 : 1) + 2;   // global_load_lds per STAGE per wave

  // T1: bijective XCD-aware swizzle (m204) over the flattened grid.
  int gx = gridDim.x, gy = gridDim.y;
  int nwg = gx * gy * gridDim.z;
  int orig = blockIdx.x + gx * (blockIdx.y + gy * blockIdx.z);
  int q = nwg >> 3, r = nwg & 7, xcd = orig & 7, off = orig >> 3;
  int wgid = (xcd < r ? xcd * (q + 1) : r * (q + 1) + (xcd - r) * q) + off;
  int bxi = wgid % gx; int tmp = wgid / gx;
  int byi = tmp % gy;  int bzi = tmp / gy;

  int z = bzi;
  int bo = z / nbi, bi = z - bo * nbi;
  int m0 = byi * BM, n0 = bxi * 128;

  const u16* Ab;
  long coff;
  void* Cbase;
  if constexpr (MERGE) {
    if (bi == 0) {
      if (m0 >= Mq) return;            // Q part has fewer rows
      Ab = A;
      coff = 0; Cbase = Cv;
    } else {
      if (MLEN && (m0 & 511) >= mlens[m0 >> 9]) return;
      Ab = A2;
      coff = (long)(bi - 1) * batCi; Cbase = Cv2;
    }
  } else {
    if constexpr (MLEN) {
      if ((m0 & 511) >= mlens[m0 >> 9]) return;
    }
    Ab = A + bo * batAo + bi * batAi;
    coff = bo * batCo + bi * batCi;
    Cbase = Cv;
  }
  const u16* Bb = Bt + bo * batBo + bi * batBi;
  const float* bias = nullptr;
  if constexpr (BIAS) bias = (bi == 0) ? bias0 : ((bi == 1) ? bias1 : bias2);

  __shared__ __align__(16) u16 As[3][BM * 32];
  __shared__ __align__(16) u16 Bs[3][128 * 32];

  int tid = threadIdx.x;
  int lane = tid & 63, wid = tid >> 6;
  int wm = wid >> 1, wn = wid & 1;
  int fr = lane & 15, grp = lane >> 4;

  f32x4 acc[BMW][4];
#pragma unroll
  for (int i = 0; i < BMW; i++)
#pragma unroll
    for (int j = 0; j < 4; j++) acc[i][j] = (f32x4){0.f, 0.f, 0.f, 0.f};

  const u16* ga = Ab + (long)(m0 + (tid >> 2)) * lda + ((tid & 3) << 3);
  const u16* gb = Bb + (long)(n0 + (tid >> 2)) * ldb + ((tid & 3) << 3);

  auto STAGE = [&](int buf, int kt) {
    u16* lA = &As[buf][tid * 8];
    u16* lB = &Bs[buf][tid * 8];
    gload16(ga + kt, lA);
    if constexpr (BM == 128) gload16(ga + kt + (long)64 * lda, lA + 2048);
    gload16(gb + kt, lB);
    gload16(gb + kt + (long)64 * ldb, lB + 2048);
  };

  auto COMPUTE = [&](int buf) {
    short8 av[BMW], bv[4];
#pragma unroll
    for (int i = 0; i < BMW; i++)
      av[i] = *(const short8*)&As[buf][(wm * BMW * 16 + i * 16 + fr) * 32 + grp * 8];
#pragma unroll
    for (int j = 0; j < 4; j++)
      bv[j] = *(const short8*)&Bs[buf][(wn * 64 + j * 16 + fr) * 32 + grp * 8];
#pragma unroll
    for (int i = 0; i < BMW; i++)
#pragma unroll
      for (int j = 0; j < 4; j++)
        acc[i][j] = __builtin_amdgcn_mfma_f32_16x16x32_bf16(av[i], bv[j], acc[i][j], 0, 0, 0);
  };

  int NT = K >> 5;                 // K/32 k-steps; all call sites have NT >= 16
  STAGE(0, 0);
  STAGE(1, 32);
  int cbuf = 0, sbuf = 2, kt = 64;
  for (int t = 0; t < NT - 2; ++t) {
    STAGE(sbuf, kt); kt += 32;     // tile t+2 into ring
    waitv<2 * LPS>();              // tile t's loads complete; t+1,t+2 stay in flight
    barrier_fenced();              // buf ready for all waves
    COMPUTE(cbuf);
    lgk0_barrier();                // all waves done reading buf (WAR for next STAGE)
    sbuf = cbuf; cbuf = (cbuf == 2) ? 0 : cbuf + 1;
  }
  waitv<LPS>();  barrier_fenced(); COMPUTE(cbuf); lgk0_barrier();
  cbuf = (cbuf == 2) ? 0 : cbuf + 1;
  waitv<0>();    barrier_fenced(); COMPUTE(cbuf);

  int rbase = m0 + wm * BMW * 16 + grp * 4;
  int cbase = n0 + wn * 64 + fr;
#pragma unroll
  for (int i = 0; i < BMW; i++) {
#pragma unroll
    for (int j = 0; j < 4; j++) {
      int col = cbase + j * 16;
      if (NCH && col >= N) continue;
      float bb = 0.0f;
      if constexpr (BIAS) bb = bias[col];
#pragma unroll
      for (int r2 = 0; r2 < 4; r2++) {
        int row = rbase + i * 16 + r2;
        float v = acc[i][j][r2] + bb;
        long idx = coff + (long)row * ldc + col;
        if constexpr (RES) v += R[idx];
        if constexpr (SWISH) v = v / (1.0f + expf(-v));
        if constexpr (OMODE == 0) ((u16*)Cbase)[idx] = bfc(v);
        else ((float*)Cbase)[idx] = v;
      }
    }
  }
}

// ---------------- fused flash attention ----------------
// Grid (b*H, qb). 256 thr = 4 waves; each wave owns WR=16*IQ q rows.
// Q/K/V all token-major [.,512] bf16 (col = h*64+d); V transposed into LDS at staging.
// O: [token][512]. Causal P zero-pad: frags j in [jmax, 2*kvmax) written as 0 so the
// PV reads never see stale LDS (jmax*16 need not equal kvmax*32 for IQ==1).
template <int SKV, int KVBLK, bool CAUSAL, int IQ>
__global__ __launch_bounds__(256) void fattn_k(
    const u16* __restrict__ Q, const u16* __restrict__ Kg, const u16* __restrict__ Vg,
    u16* __restrict__ O, const int* __restrict__ lens) {
  constexpr int NJ  = KVBLK / 16;   // S col fragments per tile
  constexpr int NKV = KVBLK / 32;   // PV k-steps per tile
  constexpr int NT  = SKV / KVBLK;  // tiles
  constexpr int KST = 72;           // K lds row stride (u16), padded
  constexpr int VST = KVBLK + 8;    // Vt / P lds row stride (u16), padded
  constexpr int WR  = 16 * IQ;      // q rows per wave
  constexpr int WGR = 64 * IQ;      // q rows per workgroup
  constexpr int CH  = KVBLK / 32;   // 16B chunks per thread for K tile (= V tile)

  __shared__ __align__(16) u16 Ks[KVBLK * KST];
  __shared__ __align__(16) u16 Vs[64 * VST];
  __shared__ __align__(16) u16 Ps[WGR * VST];

  int bh = blockIdx.x; int b = bh >> 3, h = bh & 7;
  int row00 = blockIdx.y * WGR;
  int tid = threadIdx.x, lane = tid & 63, wid = tid >> 6;
  int fr = lane & 15, grp = lane >> 4;
  int len = lens[b];
  int row0w = row00 + wid * WR;

  // Q fragments: row = row0w + i*16 + fr, elems d = k2*32 + grp*8
  short8 qa[IQ][2];
  {
    const u16* qp = Q + ((long)b * Tc + row0w + fr) * 512 + h * 64 + grp * 8;
#pragma unroll
    for (int i = 0; i < IQ; i++)
#pragma unroll
      for (int k2 = 0; k2 < 2; k2++)
        qa[i][k2] = *(const short8*)(qp + (long)i * 16 * 512 + k2 * 32);
  }

  float m_run[IQ][4], l_run[IQ][4];
  f32x4 acc_o[IQ][4];
#pragma unroll
  for (int i = 0; i < IQ; i++)
#pragma unroll
    for (int r = 0; r < 4; r++) { m_run[i][r] = -1e30f; l_run[i][r] = 0.0f; }
#pragma unroll
  for (int i = 0; i < IQ; i++)
#pragma unroll
    for (int j = 0; j < 4; j++) acc_o[i][j] = (f32x4){0.f, 0.f, 0.f, 0.f};

  const u16* Kbase = Kg + ((long)b * SKV) * 512 + h * 64;
  const u16* Vbase = Vg + ((long)b * SKV) * 512 + h * 64;

  // tile count: causal bound (wg-uniform) and len bound (wg-uniform)
  int NTeff = NT;
  if constexpr (CAUSAL) NTeff = (row00 + WGR - 1) / KVBLK + 1;
  if (NTeff > NT) NTeff = NT;
  int lenT = (len + KVBLK - 1) / KVBLK;   // tiles wholly beyond len contribute 0
  if (lenT < NTeff) NTeff = lenT;

  short8 kreg[CH], vreg[CH];
  // preload tile 0 (K rows coalesced; V rows coalesced, transposed at LDS write)
#pragma unroll
  for (int c = 0; c < CH; c++) {
    int idx = tid + 256 * c; int kv = idx >> 3, s = idx & 7;
    kreg[c] = *(const short8*)(Kbase + (long)kv * 512 + s * 8);
    vreg[c] = *(const short8*)(Vbase + (long)kv * 512 + s * 8);
  }

  for (int t = 0; t < NTeff; t++) {
    int kv0 = t * KVBLK;
    __syncthreads();  // prior-tile LDS reads done (all waves)
#pragma unroll
    for (int c = 0; c < CH; c++) {
      int idx = tid + 256 * c; int kv = idx >> 3, s = idx & 7;
      *(short8*)&Ks[kv * KST + s * 8] = kreg[c];
#pragma unroll
      for (int j = 0; j < 8; j++)
        Vs[(s * 8 + j) * VST + kv] = (u16)vreg[c][j];   // transpose: Vs[d][kv]
    }
    __syncthreads();  // LDS ready
    // prefetch next tile into regs (overlaps with compute below)
    if (t + 1 < NTeff) {
      int kvn = kv0 + KVBLK;
#pragma unroll
      for (int c = 0; c < CH; c++) {
        int idx = tid + 256 * c; int kv = idx >> 3, s = idx & 7;
        kreg[c] = *(const short8*)(Kbase + (long)(kvn + kv) * 512 + s * 8);
        vreg[c] = *(const short8*)(Vbase + (long)(kvn + kv) * 512 + s * 8);
      }
    }

    int jmax = NJ, kvmax = NKV, jmaxW = NJ;
    if constexpr (CAUSAL) {
      jmax = (row0w + WR - 1 - kv0) / 16 + 1;
      if (jmax > NJ) jmax = NJ;
      kvmax = (row0w + WR - 1 - kv0) / 32 + 1;
      if (kvmax > NKV) kvmax = NKV;
      jmaxW = 2 * kvmax;
      if (jmaxW > NJ) jmaxW = NJ;
    }

    // ---- S = Q @ K^T ----
    f32x4 accs[IQ][NJ];
    __builtin_amdgcn_s_setprio(1);
#pragma unroll
    for (int j = 0; j < NJ; j++) {
      if (CAUSAL && j >= jmax) continue;
      short8 bv0 = *(const short8*)&Ks[(j * 16 + fr) * KST + grp * 8];
      short8 bv1 = *(const short8*)&Ks[(j * 16 + fr) * KST + 32 + grp * 8];
#pragma unroll
      for (int i = 0; i < IQ; i++) {
        f32x4 a = __builtin_amdgcn_mfma_f32_16x16x32_bf16(qa[i][0], bv0, (f32x4){0.f,0.f,0.f,0.f}, 0, 0, 0);
        accs[i][j] = __builtin_amdgcn_mfma_f32_16x16x32_bf16(qa[i][1], bv1, a, 0, 0, 0);
      }
    }
    __builtin_amdgcn_s_setprio(0);

    // ---- online softmax ----
    float alpha[IQ][4];
#pragma unroll
    for (int i = 0; i < IQ; i++) {
#pragma unroll
      for (int r = 0; r < 4; r++) {
        int qrow = row0w + i * 16 + grp * 4 + r;
        float vmax = -1e30f;
#pragma unroll
        for (int j = 0; j < NJ; j++) {
          if (CAUSAL && j >= jmax) continue;
          int kvb = kv0 + j * 16 + fr;
          float s = accs[i][j][r] * 0.125f;
          bool msk = (kvb >= len) || (CAUSAL && kvb > qrow);
          s = msk ? -1e30f : s;
          accs[i][j][r] = s;
          vmax = fmaxf(vmax, s);
        }
        vmax = fmaxf(vmax, __shfl_xor(vmax, 1));
        vmax = fmaxf(vmax, __shfl_xor(vmax, 2));
        vmax = fmaxf(vmax, __shfl_xor(vmax, 4));
        vmax = fmaxf(vmax, __shfl_xor(vmax, 8));
        float mn = fmaxf(m_run[i][r], vmax);
        float al = __expf(m_run[i][r] - mn);
        m_run[i][r] = mn;
        alpha[i][r] = al;
        float rs = 0.0f;
#pragma unroll
        for (int j = 0; j < NJ; j++) {
          if (CAUSAL && j >= jmax) continue;
          float p = __expf(accs[i][j][r] - mn);
          accs[i][j][r] = p;
          rs += p;
        }
        rs += __shfl_xor(rs, 1);
        rs += __shfl_xor(rs, 2);
        rs += __shfl_xor(rs, 4);
        rs += __shfl_xor(rs, 8);
        l_run[i][r] = l_run[i][r] * al + rs;
      }
    }

    // ---- write P (bf16) to per-wave LDS region (zero-pad [jmax, jmaxW)) ----
#pragma unroll
    for (int i = 0; i < IQ; i++)
#pragma unroll
      for (int j = 0; j < NJ; j++) {
        if (CAUSAL && j >= jmaxW) continue;
#pragma unroll
        for (int r = 0; r < 4; r++) {
          int prow = wid * WR + i * 16 + grp * 4 + r;
          float pv = (CAUSAL && j >= jmax) ? 0.0f : accs[i][j][r];
          Ps[prow * VST + j * 16 + fr] = bfc(pv);
        }
      }

    // ---- rescale O ----
#pragma unroll
    for (int i = 0; i < IQ; i++)
#pragma unroll
      for (int jd = 0; jd < 4; jd++)
#pragma unroll
        for (int r = 0; r < 4; r++)
          acc_o[i][jd][r] *= alpha[i][r];

    // ---- O += P @ V ----
    __builtin_amdgcn_s_setprio(1);
#pragma unroll
    for (int kk = 0; kk < NKV; kk++) {
      if (CAUSAL && kk >= kvmax) continue;
      short8 pa[IQ];
#pragma unroll
      for (int i = 0; i < IQ; i++)
        pa[i] = *(const short8*)&Ps[(wid * WR + i * 16 + fr) * VST + kk * 32 + grp * 8];
#pragma unroll
      for (int jd = 0; jd < 4; jd++) {
        short8 vb = *(const short8*)&Vs[(jd * 16 + fr) * VST + kk * 32 + grp * 8];
#pragma unroll
        for (int i = 0; i < IQ; i++)
          acc_o[i][jd] = __builtin_amdgcn_mfma_f32_16x16x32_bf16(pa[i], vb, acc_o[i][jd], 0, 0, 0);
      }
    }
    __builtin_amdgcn_s_setprio(0);
  }

  // ---- finalize: O / l ----
#pragma unroll
  for (int i = 0; i < IQ; i++) {
#pragma unroll
    for (int r = 0; r < 4; r++) {
      float inv = 1.0f / l_run[i][r];
      long tok = (long)b * Tc + row0w + i * 16 + grp * 4 + r;
#pragma unroll
      for (int jd = 0; jd < 4; jd++)
        O[tok * 512 + h * 64 + jd * 16 + fr] = bfc(acc_o[i][jd][r] * inv);
    }
  }
}

// ---------------- host launcher ----------------
extern "C" void kernel_launch(void* const* d_in, const int* in_sizes, int n_in,
                              void* d_out, int out_size, void* d_ws, size_t ws_size,
                              hipStream_t stream) {
  const float* memory   = (const float*)d_in[0];
  const int*   mem_lens = (const int*)d_in[1];
  const int*   ys       = (const int*)d_in[2];
  const int*   ys_lens  = (const int*)d_in[3];
  const float* emb      = (const float*)d_in[4];
  const float* w_out    = (const float*)d_in[5];
  const float* b_out    = (const float*)d_in[6];
  const float* pp[26];
  for (int i = 0; i < 26; i++) pp[i] = (const float*)d_in[7 + i];

  // ---- ws layout (~126.4 MB of the 256 MiB ws) ----
  constexpr long PLW = 4194304;  // bf16 elems of transposed weights per layer
  constexpr long OFF_SAQ = 0, OFF_SAK = 262144, OFF_SAV = 524288, OFF_SAO = 786432,
                 OFF_CAQ = 1048576, OFF_CAK = 1310720, OFF_CAV = 1572864,
                 OFF_CAO = 1835008, OFF_FF1 = 2097152, OFF_FF2 = 3145728,
                 OFF_WOUT = 6 * PLW;
  u16*   Wt   = (u16*)d_ws;                          // 25,427,968 u16
  float* X    = (float*)(Wt + 25427968);             // 2,097,152 f32
  u16*   TO   = (u16*)(X + 2097152);                 // 2,097,152 bf16
  u16*   QKV  = TO + 2097152;                        // 3 x 2,097,152 bf16
  u16*   memb = QKV + 3 * 2097152;                   // 8,388,608 bf16
  u16*   Kb   = memb + 8388608;                      // 8,388,608 bf16 (cross K)
  u16*   SCR  = Kb + 8388608;                        // 8,388,608 bf16 (CA V / FF hidden)
  float* OUT  = (float*)d_out;

  // 8 square (512x512) weight families in one dispatch (z = widx*6 + l)
  PtrPack8 P8;
  P8.p[0] = pp[2];  P8.p[1] = pp[4];  P8.p[2] = pp[6];  P8.p[3] = pp[8];
  P8.p[4] = pp[12]; P8.p[5] = pp[14]; P8.p[6] = pp[16]; P8.p[7] = pp[18];
  wtrans8_k<<<dim3(16, 16, 48), 256, 0, stream>>>(P8, Wt, PLW);
  wtrans_k<<<dim3(64, 16, Lc), 256, 0, stream>>>(pp[22], Wt + OFF_FF1, 512, 2048, 1048576, PLW);
  wtrans_k<<<dim3(16, 64, Lc), 256, 0, stream>>>(pp[24], Wt + OFF_FF2, 2048, 512, 1048576, PLW);
  wtrans_k<<<dim3(16, 16, 1), 256, 0, stream>>>(w_out, Wt + OFF_WOUT, 512, 500, 0, 0);

  f2b_k<<<(NMEM * Dc / 4 + 255) / 256, 256, 0, stream>>>(memory, memb, (long)NMEM * Dc);
  embed_pe_k<<<NTOK, 256, 0, stream>>>(ys, emb, X);

  for (int l = 0; l < Lc; l++) {
    const u16* WtL = Wt + (long)l * PLW;

    // ======== self-attention ========
    layernorm_k<<<NTOK, 256, 0, stream>>>(X, pp[0] + (long)l * Dc, pp[1] + (long)l * Dc, TO);
    mgemm_k<4, 0, true, false, false, false, false, false><<<dim3(4, 32, 3), 256, 0, stream>>>(
        TO, WtL + OFF_SAQ, pp[3] + (long)l * Ac, pp[5] + (long)l * Ac, pp[7] + (long)l * Ac,
        QKV, nullptr, nullptr, nullptr, nullptr, 0,
        512, 512, 512, 512, 512, 3, 0, 0, 0, 262144, 0, 2097152);
    fattn_k<128, 128, true, 1><<<dim3(256, 2), 256, 0, stream>>>(
        QKV, QKV + 2097152, QKV + 2 * 2097152, TO, ys_lens);
    mgemm_k<2, 1, true, true, false, false, false, false><<<dim3(4, 64, 1), 256, 0, stream>>>(
        TO, WtL + OFF_SAO, pp[9] + (long)l * Dc, nullptr, nullptr, X, X, nullptr,
        nullptr, nullptr, 0,
        512, 512, 512, 512, 512, 1, 0, 0, 0, 0, 0, 0);

    // ======== cross-attention ========
    layernorm_k<<<NTOK, 256, 0, stream>>>(X, pp[10] + (long)l * Dc, pp[11] + (long)l * Dc, TO);
    // merged Q (bi=0, A=TO -> QKV) + K,V (bi=1,2, A2=memb -> Kb, SCR)
    mgemm_k<4, 0, true, false, false, false, true, true><<<dim3(4, 128, 3), 256, 0, stream>>>(
        TO, WtL + OFF_CAQ, pp[13] + (long)l * Ac, pp[15] + (long)l * Ac, pp[17] + (long)l * Ac,
        QKV, nullptr, mem_lens, memb, Kb, 4096,
        512, 512, 512, 512, 512, 3, 0, 0, 0, 262144, 0, 8388608);
    fattn_k<512, 128, false, 1><<<dim3(256, 2), 256, 0, stream>>>(
        QKV, Kb, SCR, TO, mem_lens);
    mgemm_k<2, 1, true, true, false, false, false, false><<<dim3(4, 64, 1), 256, 0, stream>>>(
        TO, WtL + OFF_CAO, pp[19] + (long)l * Dc, nullptr, nullptr, X, X, nullptr,
        nullptr, nullptr, 0,
        512, 512, 512, 512, 512, 1, 0, 0, 0, 0, 0, 0);

    // ======== feed-forward ========
    layernorm_k<<<NTOK, 256, 0, stream>>>(X, pp[20] + (long)l * Dc, pp[21] + (long)l * Dc, TO);
    mgemm_k<4, 0, true, false, true, false, false, false><<<dim3(16, 32, 1), 256, 0, stream>>>(
        TO, WtL + OFF_FF1, pp[23] + (long)l * FFc, nullptr, nullptr, SCR, nullptr, nullptr,
        nullptr, nullptr, 0,
        2048, 512, 512, 512, 2048, 1, 0, 0, 0, 0, 0, 0);
    mgemm_k<2, 1, true, true, false, false, false, false><<<dim3(4, 64, 1), 256, 0, stream>>>(
        SCR, WtL + OFF_FF2, pp[25] + (long)l * Dc, nullptr, nullptr, X, X, nullptr,
        nullptr, nullptr, 0,
        512, 2048, 2048, 2048, 512, 1, 0, 0, 0, 0, 0, 0);
  }

  // final projection: X -> bf16 -> logits fp32 (N=500, ldc=500)
  f2b_k<<<(NTOK * Dc / 4 + 255) / 256, 256, 0, stream>>>(X, TO, (long)NTOK * Dc);
  mgemm_k<2, 1, true, false, false, true, false, false><<<dim3(4, 64, 1), 256, 0, stream>>>(
      TO, Wt + OFF_WOUT, b_out, nullptr, nullptr, OUT, nullptr, nullptr,
      nullptr, nullptr, 0,
      500, 512, 512, 512, 500, 1, 0, 0, 0, 0, 0, 0);
}

// Round 14
// 1167.360 us; speedup vs baseline: 1.1338x; 1.0271x over previous
//
#include <hip/hip_runtime.h>
#include <hip/hip_bf16.h>
#include <hip/hip_fp16.h>

// ---------------- problem constants ----------------
constexpr int Bc = 32, Sc = 512, Tc = 128, Dc = 512, Ac = 512, Hc = 8;
constexpr int HDc = 64, FFc = 2048, Lc = 6, Vc = 500;
constexpr int NTOK = Bc * Tc;   // 4096
constexpr int NMEM = Bc * Sc;   // 16384

typedef unsigned short u16;
typedef __attribute__((ext_vector_type(8))) short short8;  // 8 bf16 (4 VGPRs)
typedef __attribute__((ext_vector_type(4))) float f32x4;   // MFMA accumulator

__device__ __forceinline__ u16 bfc(float x) {
  __hip_bfloat16 h = __float2bfloat16(x);
  return *reinterpret_cast<u16*>(&h);
}

// async global->LDS, 16B per lane. LDS dest = wave-uniform base + lane*16.
__device__ __forceinline__ void gload16(const void* g, void* l) {
  __builtin_amdgcn_global_load_lds(
      (const __attribute__((address_space(1))) unsigned int*)g,
      (__attribute__((address_space(3))) unsigned int*)l, 16, 0, 0);
}

// counted vmcnt wait + scheduler fence (rule #18: sched_barrier after inline waitcnt)
template <int N>
__device__ __forceinline__ void waitv() {
  if constexpr (N == 8)      asm volatile("s_waitcnt vmcnt(8)" ::: "memory");
  else if constexpr (N == 6) asm volatile("s_waitcnt vmcnt(6)" ::: "memory");
  else if constexpr (N == 4) asm volatile("s_waitcnt vmcnt(4)" ::: "memory");
  else if constexpr (N == 3) asm volatile("s_waitcnt vmcnt(3)" ::: "memory");
  else                       asm volatile("s_waitcnt vmcnt(0)" ::: "memory");
  __builtin_amdgcn_sched_barrier(0);
}
__device__ __forceinline__ void barrier_fenced() {
  __builtin_amdgcn_s_barrier();
  __builtin_amdgcn_sched_barrier(0);
}
__device__ __forceinline__ void lgk0_barrier() {
  asm volatile("s_waitcnt lgkmcnt(0)" ::: "memory");
  __builtin_amdgcn_sched_barrier(0);
  __builtin_amdgcn_s_barrier();
  __builtin_amdgcn_sched_barrier(0);
}

__device__ __forceinline__ float wave_sum(float v) {
#pragma unroll
  for (int o = 32; o > 0; o >>= 1) v += __shfl_down(v, o);
  return v;
}

// ---------------- embedding + sinusoidal PE (fp32 residual stream) ----------------
__global__ __launch_bounds__(256) void embed_pe_k(const int* __restrict__ ys,
                                                  const float* __restrict__ emb,
                                                  float* __restrict__ x) {
  int tok = blockIdx.x;
  int t = tok & (Tc - 1);
  int id = ys[tok];
  int j = threadIdx.x;
  int d0 = 2 * j;
  const float cdiv = -9.210340371976184f / (float)Dc;
  float div = expf((float)d0 * cdiv);
  float ang = (float)t * div;
  float pe0 = sinf(ang), pe1 = cosf(ang);
  const float sc = 22.627416997969522f;  // sqrt(512)
  long base = (long)tok * Dc + d0;
  long ebase = (long)id * Dc + d0;
  x[base]     = emb[ebase]     * sc + pe0;
  x[base + 1] = emb[ebase + 1] * sc + pe1;
}

// ---------------- layernorm fp32 -> bf16 (one-pass: sum + sumsq together) ----------------
__global__ __launch_bounds__(256) void layernorm_k(const float* __restrict__ x,
                                                   const float* __restrict__ g,
                                                   const float* __restrict__ bta,
                                                   u16* __restrict__ out) {
  int row = blockIdx.x;
  int tid = threadIdx.x;
  const float* xr = x + (long)row * Dc;
  float2 xv = *(const float2*)(xr + tid * 2);
  float s  = xv.x + xv.y;
  float s2 = xv.x * xv.x + xv.y * xv.y;
  __shared__ float red[4], red2[4];
#pragma unroll
  for (int o = 32; o > 0; o >>= 1) {
    s  += __shfl_down(s, o);
    s2 += __shfl_down(s2, o);
  }
  if ((tid & 63) == 0) { red[tid >> 6] = s; red2[tid >> 6] = s2; }
  __syncthreads();
  float mean = (red[0] + red[1] + red[2] + red[3]) * (1.0f / Dc);
  float ms   = (red2[0] + red2[1] + red2[2] + red2[3]) * (1.0f / Dc);
  float var  = ms - mean * mean;
  float rstd = rsqrtf(var + 1e-5f);
  float dx0 = xv.x - mean, dx1 = xv.y - mean;
  ushort2 o;
  o.x = bfc(dx0 * rstd * g[2 * tid] + bta[2 * tid]);
  o.y = bfc(dx1 * rstd * g[2 * tid + 1] + bta[2 * tid + 1]);
  *(ushort2*)(out + (long)row * Dc + tid * 2) = o;
}

// ---------------- weight transpose+convert: W(K x N) fp32 -> Wt(Npad x K) bf16 ----------------
__global__ __launch_bounds__(256) void wtrans_k(const float* __restrict__ src,
                                                u16* __restrict__ dst,
                                                int K, int N, long srcStride, long dstStride) {
  int z = blockIdx.z;
  src += z * srcStride;
  dst += z * dstStride;
  __shared__ float t[32][33];
  int n0 = blockIdx.x * 32, k0 = blockIdx.y * 32;
  int tx = threadIdx.x & 31, ty = threadIdx.x >> 5;  // 32 x 8
#pragma unroll
  for (int i = 0; i < 4; i++) {
    int n = n0 + tx;
    t[ty + 8 * i][tx] = (n < N) ? src[(long)(k0 + ty + 8 * i) * N + n] : 0.0f;
  }
  __syncthreads();
#pragma unroll
  for (int i = 0; i < 4; i++) {
    dst[(long)(n0 + ty + 8 * i) * K + k0 + tx] = bfc(t[tx][ty + 8 * i]);
  }
}

// ---------------- batched 512x512 weight transpose: 8 weight sets x 6 layers ----------------
struct PtrPack8 { const float* p[8]; };
__global__ __launch_bounds__(256) void wtrans8_k(PtrPack8 P, u16* __restrict__ Wt,
                                                 long PLW) {
  int z = blockIdx.z;            // widx*6 + l
  int widx = z / 6, l = z - widx * 6;
  const float* src = P.p[widx] + (long)l * 262144;
  u16* dst = Wt + (long)widx * 262144 + (long)l * PLW;
  __shared__ float t[32][33];
  int n0 = blockIdx.x * 32, k0 = blockIdx.y * 32;
  int tx = threadIdx.x & 31, ty = threadIdx.x >> 5;
#pragma unroll
  for (int i = 0; i < 4; i++)
    t[ty + 8 * i][tx] = src[(long)(k0 + ty + 8 * i) * 512 + n0 + tx];
  __syncthreads();
#pragma unroll
  for (int i = 0; i < 4; i++)
    dst[(long)(n0 + ty + 8 * i) * 512 + k0 + tx] = bfc(t[tx][ty + 8 * i]);
}

// ---------------- fp32 -> bf16 convert ----------------
__global__ __launch_bounds__(256) void f2b_k(const float* __restrict__ in,
                                             u16* __restrict__ out, long n) {
  long i = ((long)blockIdx.x * 256 + threadIdx.x) * 4;
  if (i >= n) return;
  float4 v = *(const float4*)(in + i);
  ushort4 o;
  o.x = bfc(v.x); o.y = bfc(v.y); o.z = bfc(v.z); o.w = bfc(v.w);
  *(ushort4*)(out + i) = o;
}

// ---------------- bf16 MFMA GEMM: 3-buffer ring, prefetch-2, counted vmcnt, T1 swizzle ----
// 4 waves / 256 threads, BM = BMW*32, BN = 128. (R6/R8/R11/R13-proven schedule, 48KB LDS.)
// Measured regressions from here: 4-buffer ring (R7), 8-wave BM=256 (R10), LN-fold (R12).
// MERGE (CA QKV): flat-y part mapping with ZERO dead blocks (R14 fix; R13 had 384 dead
// Q-part wgs): byi in [0,128) -> K (bi=1), [128,256) -> V (bi=2), [256,288) -> Q (bi=0).
template <int BMW, int OMODE, bool BIAS, bool RES, bool SWISH, bool NCH, bool MLEN, bool MERGE>
__global__ __launch_bounds__(256) void mgemm_k(
    const u16* __restrict__ A, const u16* __restrict__ Bt,
    const float* __restrict__ bias0, const float* __restrict__ bias1,
    const float* __restrict__ bias2,
    void* __restrict__ Cv, const float* __restrict__ R, const int* __restrict__ mlens,
    const u16* __restrict__ A2, void* __restrict__ Cv2, int Mq,
    int N, int K, int lda, int ldb, int ldc, int nbi,
    long batAo, long batAi, long batBo, long batBi, long batCo, long batCi) {
  constexpr int BM = BMW * 32;
  constexpr int LPS = (BM == 128 ? 2 : 1) + 2;   // global_load_lds per STAGE per wave

  // T1: bijective XCD-aware swizzle (m204) over the flattened grid.
  int gx = gridDim.x, gy = gridDim.y;
  int nwg = gx * gy * gridDim.z;
  int orig = blockIdx.x + gx * (blockIdx.y + gy * blockIdx.z);
  int q = nwg >> 3, r = nwg & 7, xcd = orig & 7, off = orig >> 3;
  int wgid = (xcd < r ? xcd * (q + 1) : r * (q + 1) + (xcd - r) * q) + off;
  int bxi = wgid % gx; int tmp = wgid / gx;
  int byi = tmp % gy;  int bzi = tmp / gy;

  int z = bzi;
  int bo = z / nbi, bi = z - bo * nbi;
  int m0 = byi * BM, n0 = bxi * 128;

  const u16* Ab;
  long coff;
  void* Cbase;
  if constexpr (MERGE) {
    // zero-dead-block flat-y mapping (grid y = 288, z = 1): K | V | Q parts
    if (byi < 256) {
      bi = 1 + (byi >> 7);             // 1 = K, 2 = V
      m0 = (byi & 127) * BM;
      if (MLEN && (m0 & 511) >= mlens[m0 >> 9]) return;
      Ab = A2;
      coff = (long)(bi - 1) * batCi; Cbase = Cv2;
    } else {
      bi = 0;                          // Q part: 32 y-blocks (M = Mq = 4096)
      m0 = (byi - 256) * BM;
      Ab = A;
      coff = 0; Cbase = Cv;
    }
  } else {
    if constexpr (MLEN) {
      if ((m0 & 511) >= mlens[m0 >> 9]) return;
    }
    Ab = A + bo * batAo + bi * batAi;
    coff = bo * batCo + bi * batCi;
    Cbase = Cv;
  }
  const u16* Bb = Bt + bo * batBo + bi * batBi;
  const float* bias = nullptr;
  if constexpr (BIAS) bias = (bi == 0) ? bias0 : ((bi == 1) ? bias1 : bias2);

  __shared__ __align__(16) u16 As[3][BM * 32];
  __shared__ __align__(16) u16 Bs[3][128 * 32];

  int tid = threadIdx.x;
  int lane = tid & 63, wid = tid >> 6;
  int wm = wid >> 1, wn = wid & 1;
  int fr = lane & 15, grp = lane >> 4;

  f32x4 acc[BMW][4];
#pragma unroll
  for (int i = 0; i < BMW; i++)
#pragma unroll
    for (int j = 0; j < 4; j++) acc[i][j] = (f32x4){0.f, 0.f, 0.f, 0.f};

  const u16* ga = Ab + (long)(m0 + (tid >> 2)) * lda + ((tid & 3) << 3);
  const u16* gb = Bb + (long)(n0 + (tid >> 2)) * ldb + ((tid & 3) << 3);

  auto STAGE = [&](int buf, int kt) {
    u16* lA = &As[buf][tid * 8];
    u16* lB = &Bs[buf][tid * 8];
    gload16(ga + kt, lA);
    if constexpr (BM == 128) gload16(ga + kt + (long)64 * lda, lA + 2048);
    gload16(gb + kt, lB);
    gload16(gb + kt + (long)64 * ldb, lB + 2048);
  };

  auto COMPUTE = [&](int buf) {
    short8 av[BMW], bv[4];
#pragma unroll
    for (int i = 0; i < BMW; i++)
      av[i] = *(const short8*)&As[buf][(wm * BMW * 16 + i * 16 + fr) * 32 + grp * 8];
#pragma unroll
    for (int j = 0; j < 4; j++)
      bv[j] = *(const short8*)&Bs[buf][(wn * 64 + j * 16 + fr) * 32 + grp * 8];
#pragma unroll
    for (int i = 0; i < BMW; i++)
#pragma unroll
      for (int j = 0; j < 4; j++)
        acc[i][j] = __builtin_amdgcn_mfma_f32_16x16x32_bf16(av[i], bv[j], acc[i][j], 0, 0, 0);
  };

  int NT = K >> 5;                 // K/32 k-steps; all call sites have NT >= 16
  STAGE(0, 0);
  STAGE(1, 32);
  int cbuf = 0, sbuf = 2, kt = 64;
  for (int t = 0; t < NT - 2; ++t) {
    STAGE(sbuf, kt); kt += 32;     // tile t+2 into ring
    waitv<2 * LPS>();              // tile t's loads complete; t+1,t+2 stay in flight
    barrier_fenced();              // buf ready for all waves
    COMPUTE(cbuf);
    lgk0_barrier();                // all waves done reading buf (WAR for next STAGE)
    sbuf = cbuf; cbuf = (cbuf == 2) ? 0 : cbuf + 1;
  }
  waitv<LPS>();  barrier_fenced(); COMPUTE(cbuf); lgk0_barrier();
  cbuf = (cbuf == 2) ? 0 : cbuf + 1;
  waitv<0>();    barrier_fenced(); COMPUTE(cbuf);

  int rbase = m0 + wm * BMW * 16 + grp * 4;
  int cbase = n0 + wn * 64 + fr;
#pragma unroll
  for (int i = 0; i < BMW; i++) {
#pragma unroll
    for (int j = 0; j < 4; j++) {
      int col = cbase + j * 16;
      if (NCH && col >= N) continue;
      float bb = 0.0f;
      if constexpr (BIAS) bb = bias[col];
#pragma unroll
      for (int r2 = 0; r2 < 4; r2++) {
        int row = rbase + i * 16 + r2;
        float v = acc[i][j][r2] + bb;
        long idx = coff + (long)row * ldc + col;
        if constexpr (RES) v += R[idx];
        if constexpr (SWISH) v = v / (1.0f + expf(-v));
        if constexpr (OMODE == 0) ((u16*)Cbase)[idx] = bfc(v);
        else ((float*)Cbase)[idx] = v;
      }
    }
  }
}

// ---------------- fused flash attention ----------------
// Grid (b*H, qb). 256 thr = 4 waves; each wave owns WR=16*IQ q rows.
// Q/K/V all token-major [.,512] bf16 (col = h*64+d); V transposed into LDS at staging.
// O: [token][512]. Causal P zero-pad: frags j in [jmax, 2*kvmax) written as 0 so the
// PV reads never see stale LDS (jmax*16 need not equal kvmax*32 for IQ==1).
template <int SKV, int KVBLK, bool CAUSAL, int IQ>
__global__ __launch_bounds__(256) void fattn_k(
    const u16* __restrict__ Q, const u16* __restrict__ Kg, const u16* __restrict__ Vg,
    u16* __restrict__ O, const int* __restrict__ lens) {
  constexpr int NJ  = KVBLK / 16;   // S col fragments per tile
  constexpr int NKV = KVBLK / 32;   // PV k-steps per tile
  constexpr int NT  = SKV / KVBLK;  // tiles
  constexpr int KST = 72;           // K lds row stride (u16), padded
  constexpr int VST = KVBLK + 8;    // Vt / P lds row stride (u16), padded
  constexpr int WR  = 16 * IQ;      // q rows per wave
  constexpr int WGR = 64 * IQ;      // q rows per workgroup
  constexpr int CH  = KVBLK / 32;   // 16B chunks per thread for K tile (= V tile)

  __shared__ __align__(16) u16 Ks[KVBLK * KST];
  __shared__ __align__(16) u16 Vs[64 * VST];
  __shared__ __align__(16) u16 Ps[WGR * VST];

  int bh = blockIdx.x; int b = bh >> 3, h = bh & 7;
  int row00 = blockIdx.y * WGR;
  int tid = threadIdx.x, lane = tid & 63, wid = tid >> 6;
  int fr = lane & 15, grp = lane >> 4;
  int len = lens[b];
  int row0w = row00 + wid * WR;

  // Q fragments: row = row0w + i*16 + fr, elems d = k2*32 + grp*8
  short8 qa[IQ][2];
  {
    const u16* qp = Q + ((long)b * Tc + row0w + fr) * 512 + h * 64 + grp * 8;
#pragma unroll
    for (int i = 0; i < IQ; i++)
#pragma unroll
      for (int k2 = 0; k2 < 2; k2++)
        qa[i][k2] = *(const short8*)(qp + (long)i * 16 * 512 + k2 * 32);
  }

  float m_run[IQ][4], l_run[IQ][4];
  f32x4 acc_o[IQ][4];
#pragma unroll
  for (int i = 0; i < IQ; i++)
#pragma unroll
    for (int r = 0; r < 4; r++) { m_run[i][r] = -1e30f; l_run[i][r] = 0.0f; }
#pragma unroll
  for (int i = 0; i < IQ; i++)
#pragma unroll
    for (int j = 0; j < 4; j++) acc_o[i][j] = (f32x4){0.f, 0.f, 0.f, 0.f};

  const u16* Kbase = Kg + ((long)b * SKV) * 512 + h * 64;
  const u16* Vbase = Vg + ((long)b * SKV) * 512 + h * 64;

  // tile count: causal bound (wg-uniform) and len bound (wg-uniform)
  int NTeff = NT;
  if constexpr (CAUSAL) NTeff = (row00 + WGR - 1) / KVBLK + 1;
  if (NTeff > NT) NTeff = NT;
  int lenT = (len + KVBLK - 1) / KVBLK;   // tiles wholly beyond len contribute 0
  if (lenT < NTeff) NTeff = lenT;

  short8 kreg[CH], vreg[CH];
  // preload tile 0 (K rows coalesced; V rows coalesced, transposed at LDS write)
#pragma unroll
  for (int c = 0; c < CH; c++) {
    int idx = tid + 256 * c; int kv = idx >> 3, s = idx & 7;
    kreg[c] = *(const short8*)(Kbase + (long)kv * 512 + s * 8);
    vreg[c] = *(const short8*)(Vbase + (long)kv * 512 + s * 8);
  }

  for (int t = 0; t < NTeff; t++) {
    int kv0 = t * KVBLK;
    __syncthreads();  // prior-tile LDS reads done (all waves)
#pragma unroll
    for (int c = 0; c < CH; c++) {
      int idx = tid + 256 * c; int kv = idx >> 3, s = idx & 7;
      *(short8*)&Ks[kv * KST + s * 8] = kreg[c];
#pragma unroll
      for (int j = 0; j < 8; j++)
        Vs[(s * 8 + j) * VST + kv] = (u16)vreg[c][j];   // transpose: Vs[d][kv]
    }
    __syncthreads();  // LDS ready
    // prefetch next tile into regs (overlaps with compute below)
    if (t + 1 < NTeff) {
      int kvn = kv0 + KVBLK;
#pragma unroll
      for (int c = 0; c < CH; c++) {
        int idx = tid + 256 * c; int kv = idx >> 3, s = idx & 7;
        kreg[c] = *(const short8*)(Kbase + (long)(kvn + kv) * 512 + s * 8);
        vreg[c] = *(const short8*)(Vbase + (long)(kvn + kv) * 512 + s * 8);
      }
    }

    int jmax = NJ, kvmax = NKV, jmaxW = NJ;
    if constexpr (CAUSAL) {
      jmax = (row0w + WR - 1 - kv0) / 16 + 1;
      if (jmax > NJ) jmax = NJ;
      kvmax = (row0w + WR - 1 - kv0) / 32 + 1;
      if (kvmax > NKV) kvmax = NKV;
      jmaxW = 2 * kvmax;
      if (jmaxW > NJ) jmaxW = NJ;
    }

    // ---- S = Q @ K^T ----
    f32x4 accs[IQ][NJ];
    __builtin_amdgcn_s_setprio(1);
#pragma unroll
    for (int j = 0; j < NJ; j++) {
      if (CAUSAL && j >= jmax) continue;
      short8 bv0 = *(const short8*)&Ks[(j * 16 + fr) * KST + grp * 8];
      short8 bv1 = *(const short8*)&Ks[(j * 16 + fr) * KST + 32 + grp * 8];
#pragma unroll
      for (int i = 0; i < IQ; i++) {
        f32x4 a = __builtin_amdgcn_mfma_f32_16x16x32_bf16(qa[i][0], bv0, (f32x4){0.f,0.f,0.f,0.f}, 0, 0, 0);
        accs[i][j] = __builtin_amdgcn_mfma_f32_16x16x32_bf16(qa[i][1], bv1, a, 0, 0, 0);
      }
    }
    __builtin_amdgcn_s_setprio(0);

    // ---- online softmax ----
    float alpha[IQ][4];
#pragma unroll
    for (int i = 0; i < IQ; i++) {
#pragma unroll
      for (int r = 0; r < 4; r++) {
        int qrow = row0w + i * 16 + grp * 4 + r;
        float vmax = -1e30f;
#pragma unroll
        for (int j = 0; j < NJ; j++) {
          if (CAUSAL && j >= jmax) continue;
          int kvb = kv0 + j * 16 + fr;
          float s = accs[i][j][r] * 0.125f;
          bool msk = (kvb >= len) || (CAUSAL && kvb > qrow);
          s = msk ? -1e30f : s;
          accs[i][j][r] = s;
          vmax = fmaxf(vmax, s);
        }
        vmax = fmaxf(vmax, __shfl_xor(vmax, 1));
        vmax = fmaxf(vmax, __shfl_xor(vmax, 2));
        vmax = fmaxf(vmax, __shfl_xor(vmax, 4));
        vmax = fmaxf(vmax, __shfl_xor(vmax, 8));
        float mn = fmaxf(m_run[i][r], vmax);
        float al = __expf(m_run[i][r] - mn);
        m_run[i][r] = mn;
        alpha[i][r] = al;
        float rs = 0.0f;
#pragma unroll
        for (int j = 0; j < NJ; j++) {
          if (CAUSAL && j >= jmax) continue;
          float p = __expf(accs[i][j][r] - mn);
          accs[i][j][r] = p;
          rs += p;
        }
        rs += __shfl_xor(rs, 1);
        rs += __shfl_xor(rs, 2);
        rs += __shfl_xor(rs, 4);
        rs += __shfl_xor(rs, 8);
        l_run[i][r] = l_run[i][r] * al + rs;
      }
    }

    // ---- write P (bf16) to per-wave LDS region (zero-pad [jmax, jmaxW)) ----
#pragma unroll
    for (int i = 0; i < IQ; i++)
#pragma unroll
      for (int j = 0; j < NJ; j++) {
        if (CAUSAL && j >= jmaxW) continue;
#pragma unroll
        for (int r = 0; r < 4; r++) {
          int prow = wid * WR + i * 16 + grp * 4 + r;
          float pv = (CAUSAL && j >= jmax) ? 0.0f : accs[i][j][r];
          Ps[prow * VST + j * 16 + fr] = bfc(pv);
        }
      }

    // ---- rescale O ----
#pragma unroll
    for (int i = 0; i < IQ; i++)
#pragma unroll
      for (int jd = 0; jd < 4; jd++)
#pragma unroll
        for (int r = 0; r < 4; r++)
          acc_o[i][jd][r] *= alpha[i][r];

    // ---- O += P @ V ----
    __builtin_amdgcn_s_setprio(1);
#pragma unroll
    for (int kk = 0; kk < NKV; kk++) {
      if (CAUSAL && kk >= kvmax) continue;
      short8 pa[IQ];
#pragma unroll
      for (int i = 0; i < IQ; i++)
        pa[i] = *(const short8*)&Ps[(wid * WR + i * 16 + fr) * VST + kk * 32 + grp * 8];
#pragma unroll
      for (int jd = 0; jd < 4; jd++) {
        short8 vb = *(const short8*)&Vs[(jd * 16 + fr) * VST + kk * 32 + grp * 8];
#pragma unroll
        for (int i = 0; i < IQ; i++)
          acc_o[i][jd] = __builtin_amdgcn_mfma_f32_16x16x32_bf16(pa[i], vb, acc_o[i][jd], 0, 0, 0);
      }
    }
    __builtin_amdgcn_s_setprio(0);
  }

  // ---- finalize: O / l ----
#pragma unroll
  for (int i = 0; i < IQ; i++) {
#pragma unroll
    for (int r = 0; r < 4; r++) {
      float inv = 1.0f / l_run[i][r];
      long tok = (long)b * Tc + row0w + i * 16 + grp * 4 + r;
#pragma unroll
      for (int jd = 0; jd < 4; jd++)
        O[tok * 512 + h * 64 + jd * 16 + fr] = bfc(acc_o[i][jd][r] * inv);
    }
  }
}

// ---------------- host launcher ----------------
extern "C" void kernel_launch(void* const* d_in, const int* in_sizes, int n_in,
                              void* d_out, int out_size, void* d_ws, size_t ws_size,
                              hipStream_t stream) {
  const float* memory   = (const float*)d_in[0];
  const int*   mem_lens = (const int*)d_in[1];
  const int*   ys       = (const int*)d_in[2];
  const int*   ys_lens  = (const int*)d_in[3];
  const float* emb      = (const float*)d_in[4];
  const float* w_out    = (const float*)d_in[5];
  const float* b_out    = (const float*)d_in[6];
  const float* pp[26];
  for (int i = 0; i < 26; i++) pp[i] = (const float*)d_in[7 + i];

  // ---- ws layout (~126.4 MB of the 256 MiB ws) ----
  constexpr long PLW = 4194304;  // bf16 elems of transposed weights per layer
  constexpr long OFF_SAQ = 0, OFF_SAK = 262144, OFF_SAV = 524288, OFF_SAO = 786432,
                 OFF_CAQ = 1048576, OFF_CAK = 1310720, OFF_CAV = 1572864,
                 OFF_CAO = 1835008, OFF_FF1 = 2097152, OFF_FF2 = 3145728,
                 OFF_WOUT = 6 * PLW;
  u16*   Wt   = (u16*)d_ws;                          // 25,427,968 u16
  float* X    = (float*)(Wt + 25427968);             // 2,097,152 f32
  u16*   TO   = (u16*)(X + 2097152);                 // 2,097,152 bf16
  u16*   QKV  = TO + 2097152;                        // 3 x 2,097,152 bf16
  u16*   memb = QKV + 3 * 2097152;                   // 8,388,608 bf16
  u16*   Kb   = memb + 8388608;                      // 8,388,608 bf16 (cross K)
  u16*   SCR  = Kb + 8388608;                        // 8,388,608 bf16 (CA V / FF hidden)
  float* OUT  = (float*)d_out;

  // 8 square (512x512) weight families in one dispatch (z = widx*6 + l)
  PtrPack8 P8;
  P8.p[0] = pp[2];  P8.p[1] = pp[4];  P8.p[2] = pp[6];  P8.p[3] = pp[8];
  P8.p[4] = pp[12]; P8.p[5] = pp[14]; P8.p[6] = pp[16]; P8.p[7] = pp[18];
  wtrans8_k<<<dim3(16, 16, 48), 256, 0, stream>>>(P8, Wt, PLW);
  wtrans_k<<<dim3(64, 16, Lc), 256, 0, stream>>>(pp[22], Wt + OFF_FF1, 512, 2048, 1048576, PLW);
  wtrans_k<<<dim3(16, 64, Lc), 256, 0, stream>>>(pp[24], Wt + OFF_FF2, 2048, 512, 1048576, PLW);
  wtrans_k<<<dim3(16, 16, 1), 256, 0, stream>>>(w_out, Wt + OFF_WOUT, 512, 500, 0, 0);

  f2b_k<<<(NMEM * Dc / 4 + 255) / 256, 256, 0, stream>>>(memory, memb, (long)NMEM * Dc);
  embed_pe_k<<<NTOK, 256, 0, stream>>>(ys, emb, X);

  for (int l = 0; l < Lc; l++) {
    const u16* WtL = Wt + (long)l * PLW;

    // ======== self-attention ========
    layernorm_k<<<NTOK, 256, 0, stream>>>(X, pp[0] + (long)l * Dc, pp[1] + (long)l * Dc, TO);
    mgemm_k<4, 0, true, false, false, false, false, false><<<dim3(4, 32, 3), 256, 0, stream>>>(
        TO, WtL + OFF_SAQ, pp[3] + (long)l * Ac, pp[5] + (long)l * Ac, pp[7] + (long)l * Ac,
        QKV, nullptr, nullptr, nullptr, nullptr, 0,
        512, 512, 512, 512, 512, 3, 0, 0, 0, 262144, 0, 2097152);
    fattn_k<128, 128, true, 1><<<dim3(256, 2), 256, 0, stream>>>(
        QKV, QKV + 2097152, QKV + 2 * 2097152, TO, ys_lens);
    mgemm_k<2, 1, true, true, false, false, false, false><<<dim3(4, 64, 1), 256, 0, stream>>>(
        TO, WtL + OFF_SAO, pp[9] + (long)l * Dc, nullptr, nullptr, X, X, nullptr,
        nullptr, nullptr, 0,
        512, 512, 512, 512, 512, 1, 0, 0, 0, 0, 0, 0);

    // ======== cross-attention ========
    layernorm_k<<<NTOK, 256, 0, stream>>>(X, pp[10] + (long)l * Dc, pp[11] + (long)l * Dc, TO);
    // merged QKV, flat-y grid (4, 288): K | V | Q parts, zero dead blocks
    mgemm_k<4, 0, true, false, false, false, true, true><<<dim3(4, 288, 1), 256, 0, stream>>>(
        TO, WtL + OFF_CAQ, pp[13] + (long)l * Ac, pp[15] + (long)l * Ac, pp[17] + (long)l * Ac,
        QKV, nullptr, mem_lens, memb, Kb, 4096,
        512, 512, 512, 512, 512, 1, 0, 0, 0, 262144, 0, 8388608);
    fattn_k<512, 128, false, 1><<<dim3(256, 2), 256, 0, stream>>>(
        QKV, Kb, SCR, TO, mem_lens);
    mgemm_k<2, 1, true, true, false, false, false, false><<<dim3(4, 64, 1), 256, 0, stream>>>(
        TO, WtL + OFF_CAO, pp[19] + (long)l * Dc, nullptr, nullptr, X, X, nullptr,
        nullptr, nullptr, 0,
        512, 512, 512, 512, 512, 1, 0, 0, 0, 0, 0, 0);

    // ======== feed-forward ========
    layernorm_k<<<NTOK, 256, 0, stream>>>(X, pp[20] + (long)l * Dc, pp[21] + (long)l * Dc, TO);
    mgemm_k<4, 0, true, false, true, false, false, false><<<dim3(16, 32, 1), 256, 0, stream>>>(
        TO, WtL + OFF_FF1, pp[23] + (long)l * FFc, nullptr, nullptr, SCR, nullptr, nullptr,
        nullptr, nullptr, 0,
        2048, 512, 512, 512, 2048, 1, 0, 0, 0, 0, 0, 0);
    mgemm_k<2, 1, true, true, false, false, false, false><<<dim3(4, 64, 1), 256, 0, stream>>>(
        SCR, WtL + OFF_FF2, pp[25] + (long)l * Dc, nullptr, nullptr, X, X, nullptr,
        nullptr, nullptr, 0,
        512, 2048, 2048, 2048, 512, 1, 0, 0, 0, 0, 0, 0);
  }

  // final projection: X -> bf16 -> logits fp32 (N=500, ldc=500)
  f2b_k<<<(NTOK * Dc / 4 + 255) / 256, 256, 0, stream>>>(X, TO, (long)NTOK * Dc);
  mgemm_k<2, 1, true, false, false, true, false, false><<<dim3(4, 64, 1), 256, 0, stream>>>(
      TO, Wt + OFF_WOUT, b_out, nullptr, nullptr, OUT, nullptr, nullptr,
      nullptr, nullptr, 0,
      500, 512, 512, 512, 500, 1, 0, 0, 0, 0, 0, 0);
}